// Round 3
// baseline (526.122 us; speedup 1.0000x reference)
//
#include <hip/hip_runtime.h>
#include <hip/hip_cooperative_groups.h>
#include <math.h>

namespace cg = cooperative_groups;

#define BB 16
#define TT 4096
#define EE 1024
#define HALF 2048
#define WIN 15
#define EPSF 1e-6f
#define PI_F   3.14159265358979323846f
#define PIO2_F 1.57079632679489662f
#define GRIDN 1024

// Branchless cephes-style asin: ~16 VALU ops, 1 sqrt, no divergence.
__device__ __forceinline__ float fast_asinf(float v) {
    float a  = fabsf(v);
    float z1 = a * a;
    float z2 = 0.5f * (1.0f - a);
    bool big = a > 0.5f;
    float z = big ? z2 : z1;
    float s = big ? sqrtf(z) : a;
    float p = fmaf(z, 4.2163199048e-2f, 2.4181311049e-2f);
    p = fmaf(z, p, 4.5470025998e-2f);
    p = fmaf(z, p, 7.4953002686e-2f);
    p = fmaf(z, p, 1.6666752422e-1f);
    float r = fmaf(s * z, p, s);
    float rb = fmaf(-2.0f, r, PIO2_F);
    r = big ? rb : r;
    return copysignf(r, v);
}

// ---------------------------------------------------------------------------
// Stage A: phases + c0. 4096 waves, 16 consecutive rows per wave.
// ---------------------------------------------------------------------------
__device__ __forceinline__ void stage_phase(const float* __restrict__ x,
                                            const float* __restrict__ taper,
                                            float* __restrict__ phases_T,
                                            float* __restrict__ c0_T) {
    const int lane = threadIdx.x & 63;
    const int gw = blockIdx.x * 4 + (threadIdx.x >> 6);     // 0..4095
    const float LO = -1.0f + EPSF, HI = 1.0f - EPSF;
    #pragma unroll 2
    for (int i = 0; i < 16; ++i) {
        const int row = gw * 16 + i;                        // 64 KiB contiguous / wave
        const int b = row >> 12;
        const int t = row & (TT - 1);
        const float tap = taper[t];
        const float* xr = x + (size_t)row * EE;
        const float c0 = xr[0] * tap;
        const float r = fabsf(c0) + EPSF;
        const float scale = tap / r;
        const float start = (c0 >= 0.0f) ? 0.0f : PI_F;
        const float4* xr4 = (const float4*)xr;
        float sum = 0.0f;
        #pragma unroll
        for (int j = 0; j < 4; ++j) {
            float4 v = xr4[j * 64 + lane];                  // coalesced 1 KiB/wave
            float a0 = fast_asinf(fminf(fmaxf(v.x * scale, LO), HI));
            if ((j | lane) == 0) a0 = 0.0f;                 // element 0 excluded
            sum += a0;
            sum += fast_asinf(fminf(fmaxf(v.y * scale, LO), HI));
            sum += fast_asinf(fminf(fmaxf(v.z * scale, LO), HI));
            sum += fast_asinf(fminf(fmaxf(v.w * scale, LO), HI));
        }
        #pragma unroll
        for (int off = 32; off > 0; off >>= 1)
            sum += __shfl_xor(sum, off, 64);
        if (lane == 0) {
            phases_T[t * BB + b] = start + sum;
            c0_T[t * BB + b]     = c0;
        }
    }
}

// ---------------------------------------------------------------------------
// Stage B: causal triangular moving average (window 15).
// ---------------------------------------------------------------------------
__device__ __forceinline__ void stage_tdiff(const float* __restrict__ c0_T,
                                            float* __restrict__ tdiff_T) {
    const int f = blockIdx.x * blockDim.x + threadIdx.x;    // 0..262143
    if (f >= BB * TT) return;
    const int t = f >> 4;
    const int b = f & 15;
    float num = 0.0f;
    #pragma unroll
    for (int d = 1; d <= WIN; ++d) {
        if (d <= t) num += (float)d * c0_T[(t - d) * BB + b];
    }
    const int s = (t < WIN) ? t : WIN;
    const float norm = 0.5f * (float)s * (float)(s + 1);
    tdiff_T[f] = (norm > 0.0f) ? (num / norm) : 0.0f;
}

// ---------------------------------------------------------------------------
// Stages C/D: skinny GEMM (M=16). 1024 units: 4 cols/block, 64 lanes/col.
// units 0..511 = c-path (g=0), 512..1023 = p-path (g=1).
// MODE 0: silu -> H_T[o*16+b].   MODE 1: tanh -> out[b*4096 + o*2 + g].
// ---------------------------------------------------------------------------
template <int K, int MODE>
__device__ __forceinline__ void stage_gemm(const float* __restrict__ A0,
                                           const float* __restrict__ W0,
                                           const float* __restrict__ bias0,
                                           float* __restrict__ out0,
                                           const float* __restrict__ A1,
                                           const float* __restrict__ W1,
                                           const float* __restrict__ bias1,
                                           float* __restrict__ out1,
                                           float* red) {
    const int unit = blockIdx.x;              // 0..1023
    const int g = unit >> 9;
    const int local = unit & 511;
    const int col = threadIdx.x >> 6;         // 0..3
    const int lane = threadIdx.x & 63;
    const int o = local * 4 + col;

    const float* A    = g ? A1 : A0;
    const float* W    = g ? W1 : W0;
    const float* bias = g ? bias1 : bias0;
    float* out        = g ? out1 : out0;

    const float* wrow = W + (size_t)o * K;
    const float4* A4 = (const float4*)A;

    float acc[16];
    #pragma unroll
    for (int i = 0; i < 16; ++i) acc[i] = 0.0f;

    #pragma unroll 4
    for (int k = lane; k < K; k += 64) {
        const float w = wrow[k];              // 256 B coalesced per wave
        float4 a0 = A4[k * 4 + 0];
        float4 a1 = A4[k * 4 + 1];
        float4 a2 = A4[k * 4 + 2];
        float4 a3 = A4[k * 4 + 3];
        acc[0]  += w * a0.x; acc[1]  += w * a0.y; acc[2]  += w * a0.z; acc[3]  += w * a0.w;
        acc[4]  += w * a1.x; acc[5]  += w * a1.y; acc[6]  += w * a1.z; acc[7]  += w * a1.w;
        acc[8]  += w * a2.x; acc[9]  += w * a2.y; acc[10] += w * a2.z; acc[11] += w * a2.w;
        acc[12] += w * a3.x; acc[13] += w * a3.y; acc[14] += w * a3.z; acc[15] += w * a3.w;
    }

    float* rp = red + (size_t)(col * 64 + lane) * 17;   // pad 17 -> no bank alias
    #pragma unroll
    for (int i = 0; i < 16; ++i) rp[i] = acc[i];
    __syncthreads();

    if (threadIdx.x < 64) {
        const int c2 = threadIdx.x >> 4;      // 0..3
        const int b  = threadIdx.x & 15;
        const float* q = red + (size_t)(c2 * 64) * 17 + b;
        float s = 0.0f;
        #pragma unroll
        for (int l = 0; l < 64; ++l) s += q[l * 17];
        s += bias[local * 4 + c2];
        if (MODE == 0) {
            s = s / (1.0f + expf(-s));
            out[(local * 4 + c2) * BB + b] = s;
        } else {
            s = tanhf(s);
            out[(size_t)b * (HALF * 2) + (local * 4 + c2) * 2 + g] = s;
        }
    }
    __syncthreads();
}

// ---------------------------------------------------------------------------
// Fused cooperative kernel.
// ---------------------------------------------------------------------------
__global__ void __launch_bounds__(256, 4)
fused_kernel(const float* x, const float* taper,
             const float* cW1, const float* cb1, const float* cW2, const float* cb2,
             const float* pW1, const float* pb1, const float* pW2, const float* pb2,
             float* out, float* phases_T, float* c0_T, float* tdiff_T,
             float* H1_T, float* H2_T) {
    __shared__ float red[4 * 64 * 17];
    cg::grid_group grid = cg::this_grid();
    stage_phase(x, taper, phases_T, c0_T);
    grid.sync();
    stage_tdiff(c0_T, tdiff_T);
    grid.sync();
    stage_gemm<TT, 0>(phases_T, cW1, cb1, H1_T, tdiff_T, pW1, pb1, H2_T, red);
    grid.sync();
    stage_gemm<HALF, 1>(H1_T, cW2, cb2, out, H2_T, pW2, pb2, out, red);
}

// Fallback separate-kernel path (same device code, 4 launches).
__global__ void __launch_bounds__(256, 4)
k_phase(const float* x, const float* taper, float* ph, float* c0) {
    stage_phase(x, taper, ph, c0);
}
__global__ void __launch_bounds__(256, 4)
k_tdiff(const float* c0, float* td) { stage_tdiff(c0, td); }
template <int K, int MODE>
__global__ void __launch_bounds__(256, 4)
k_gemm(const float* A0, const float* W0, const float* b0, float* o0,
       const float* A1, const float* W1, const float* b1, float* o1) {
    __shared__ float red[4 * 64 * 17];
    stage_gemm<K, MODE>(A0, W0, b0, o0, A1, W1, b1, o1, red);
}

extern "C" void kernel_launch(void* const* d_in, const int* in_sizes, int n_in,
                              void* d_out, int out_size, void* d_ws, size_t ws_size,
                              hipStream_t stream) {
    const float* x     = (const float*)d_in[0];
    const float* taper = (const float*)d_in[1];
    const float* cW1   = (const float*)d_in[2];
    const float* cb1   = (const float*)d_in[3];
    const float* cW2   = (const float*)d_in[4];
    const float* cb2   = (const float*)d_in[5];
    const float* pW1   = (const float*)d_in[6];
    const float* pb1   = (const float*)d_in[7];
    const float* pW2   = (const float*)d_in[8];
    const float* pb2   = (const float*)d_in[9];
    float* out = (float*)d_out;
    float* ws  = (float*)d_ws;

    float* phases_T = ws;                         // 65536 f32
    float* c0_T     = ws + 65536;                 // 65536
    float* tdiff_T  = ws + 131072;                // 65536
    float* H1_T     = ws + 196608;                // 32768
    float* H2_T     = ws + 229376;                // 32768

    void* args[] = {
        (void*)&x, (void*)&taper,
        (void*)&cW1, (void*)&cb1, (void*)&cW2, (void*)&cb2,
        (void*)&pW1, (void*)&pb1, (void*)&pW2, (void*)&pb2,
        (void*)&out, (void*)&phases_T, (void*)&c0_T, (void*)&tdiff_T,
        (void*)&H1_T, (void*)&H2_T,
    };
    hipError_t e = hipLaunchCooperativeKernel((const void*)fused_kernel,
                                              dim3(GRIDN), dim3(256), args, 0, stream);
    if (e != hipSuccess) {
        (void)hipGetLastError();   // clear sticky error, use fallback path
        k_phase<<<GRIDN, 256, 0, stream>>>(x, taper, phases_T, c0_T);
        k_tdiff<<<GRIDN, 256, 0, stream>>>(c0_T, tdiff_T);
        k_gemm<TT, 0><<<GRIDN, 256, 0, stream>>>(phases_T, cW1, cb1, H1_T,
                                                 tdiff_T, pW1, pb1, H2_T);
        k_gemm<HALF, 1><<<GRIDN, 256, 0, stream>>>(H1_T, cW2, cb2, out,
                                                   H2_T, pW2, pb2, out);
    }
}

// Round 4
// 182.416 us; speedup vs baseline: 2.8842x; 2.8842x over previous
//
#include <hip/hip_runtime.h>
#include <math.h>

#define BB 16
#define TT 4096
#define EE 1024
#define HALF 2048
#define WIN 15
#define EPSF 1e-6f
#define PI_F   3.14159265358979323846f
#define PIO2_F 1.57079632679489662f

// Branchless cephes-style asin: ~16 VALU ops, 1 sqrt, no divergence.
__device__ __forceinline__ float fast_asinf(float v) {
    float a  = fabsf(v);
    float z1 = a * a;
    float z2 = 0.5f * (1.0f - a);
    bool big = a > 0.5f;
    float z = big ? z2 : z1;
    float s = big ? sqrtf(z) : a;
    float p = fmaf(z, 4.2163199048e-2f, 2.4181311049e-2f);
    p = fmaf(z, p, 4.5470025998e-2f);
    p = fmaf(z, p, 7.4953002686e-2f);
    p = fmaf(z, p, 1.6666752422e-1f);
    float r = fmaf(s * z, p, s);
    float rb = fmaf(-2.0f, r, PIO2_F);
    r = big ? rb : r;
    return copysignf(r, v);
}

// ---------------------------------------------------------------------------
// Phase kernel: ONE BLOCK PER ROW. 65536 blocks x 256 threads.
// Each thread loads one float4 (issued immediately -> max loads in flight),
// ~70 VALU ops, then wave-shfl + tiny-LDS reduce. taper[t] and x[row][0]
// are block-uniform -> scalar loads, no extra vector traffic.
// ---------------------------------------------------------------------------
__global__ void __launch_bounds__(256)
phase_kernel(const float* __restrict__ x,
             const float* __restrict__ taper,
             float* __restrict__ phases_T,
             float* __restrict__ c0_T) {
    const int row = blockIdx.x;                  // 0..B*T-1
    const int b = row >> 12;
    const int t = row & (TT - 1);
    const float tap = taper[t];                  // uniform -> s_load
    const float* xr = x + (size_t)row * EE;

    float4 v = ((const float4*)xr)[threadIdx.x]; // 1 coalesced 16B load/thread

    const float x0 = xr[0];                      // uniform -> scalar path
    const float c0 = x0 * tap;
    const float r = fabsf(c0) + EPSF;
    const float scale = tap / r;
    const float LO = -1.0f + EPSF, HI = 1.0f - EPSF;

    float a0 = fast_asinf(fminf(fmaxf(v.x * scale, LO), HI));
    if (threadIdx.x == 0) a0 = 0.0f;             // element 0 (c0) excluded
    float sum = a0
              + fast_asinf(fminf(fmaxf(v.y * scale, LO), HI))
              + fast_asinf(fminf(fmaxf(v.z * scale, LO), HI))
              + fast_asinf(fminf(fmaxf(v.w * scale, LO), HI));

    #pragma unroll
    for (int off = 32; off > 0; off >>= 1)
        sum += __shfl_xor(sum, off, 64);

    __shared__ float part[4];
    if ((threadIdx.x & 63) == 0) part[threadIdx.x >> 6] = sum;
    __syncthreads();
    if (threadIdx.x == 0) {
        float tot = part[0] + part[1] + part[2] + part[3];
        const float start = (c0 >= 0.0f) ? 0.0f : PI_F;
        phases_T[t * BB + b] = start + tot;
        c0_T[t * BB + b]     = c0;
    }
}

// ---------------------------------------------------------------------------
// tdiff: causal triangular moving average (window 15). Unchanged.
// ---------------------------------------------------------------------------
__global__ void tdiff_kernel(const float* __restrict__ c0_T,
                             float* __restrict__ tdiff_T) {
    const int f = blockIdx.x * blockDim.x + threadIdx.x;   // t*16 + b
    if (f >= BB * TT) return;
    const int t = f >> 4;
    const int b = f & 15;
    float num = 0.0f;
    #pragma unroll
    for (int d = 1; d <= WIN; ++d) {
        if (d <= t) num += (float)d * c0_T[(t - d) * BB + b];
    }
    const int s = (t < WIN) ? t : WIN;
    const float norm = 0.5f * (float)s * (float)(s + 1);
    tdiff_T[f] = (norm > 0.0f) ? (num / norm) : 0.0f;
}

// ---------------------------------------------------------------------------
// Skinny GEMM (M=16), unchanged from R2 (the 164-172 us config).
// 8 output cols/block, 32 lanes stride k, padded LDS reduce.
// MODE 0: silu -> H_T[o*16+b].   MODE 1: tanh -> out[b*4096 + o*2 + g].
// ---------------------------------------------------------------------------
template <int K, int MODE>
__global__ void gemm_kernel(const float* __restrict__ A0,
                            const float* __restrict__ W0,
                            const float* __restrict__ bias0,
                            float* __restrict__ out0,
                            const float* __restrict__ A1,
                            const float* __restrict__ W1,
                            const float* __restrict__ bias1,
                            float* __restrict__ out1) {
    const int BO = 8;
    const int nb = HALF / BO;                 // 256 blocks per problem
    const int g = blockIdx.x / nb;            // which compressor
    const int obase = (blockIdx.x % nb) * BO;

    const float* A    = g ? A1 : A0;
    const float* W    = g ? W1 : W0;
    const float* bias = g ? bias1 : bias0;
    float* out        = g ? out1 : out0;

    const int og = threadIdx.x >> 5;          // 0..7 output col in block
    const int ln = threadIdx.x & 31;          // k-stripe
    const int o = obase + og;
    const float* wrow = W + (size_t)o * K;
    const float4* A4 = (const float4*)A;

    float acc[16];
    #pragma unroll
    for (int i = 0; i < 16; ++i) acc[i] = 0.0f;

    #pragma unroll 4
    for (int k = ln; k < K; k += 32) {
        const float w = wrow[k];
        float4 a0 = A4[k * 4 + 0];
        float4 a1 = A4[k * 4 + 1];
        float4 a2 = A4[k * 4 + 2];
        float4 a3 = A4[k * 4 + 3];
        acc[0]  += w * a0.x; acc[1]  += w * a0.y; acc[2]  += w * a0.z; acc[3]  += w * a0.w;
        acc[4]  += w * a1.x; acc[5]  += w * a1.y; acc[6]  += w * a1.z; acc[7]  += w * a1.w;
        acc[8]  += w * a2.x; acc[9]  += w * a2.y; acc[10] += w * a2.z; acc[11] += w * a2.w;
        acc[12] += w * a3.x; acc[13] += w * a3.y; acc[14] += w * a3.z; acc[15] += w * a3.w;
    }

    __shared__ float red[8][32][20];          // padded stride
    #pragma unroll
    for (int i = 0; i < 16; ++i) red[og][ln][i] = acc[i];
    __syncthreads();

    if (threadIdx.x < 128) {
        const int o2 = threadIdx.x >> 4;      // 0..7
        const int b  = threadIdx.x & 15;      // 0..15
        float s = 0.0f;
        #pragma unroll
        for (int j = 0; j < 32; ++j) s += red[o2][j][b];
        s += bias[obase + o2];
        if (MODE == 0) {
            s = s / (1.0f + expf(-s));        // silu
            out[(obase + o2) * BB + b] = s;
        } else {
            s = tanhf(s);
            out[(size_t)b * (HALF * 2) + (obase + o2) * 2 + g] = s;
        }
    }
}

extern "C" void kernel_launch(void* const* d_in, const int* in_sizes, int n_in,
                              void* d_out, int out_size, void* d_ws, size_t ws_size,
                              hipStream_t stream) {
    const float* x     = (const float*)d_in[0];
    const float* taper = (const float*)d_in[1];
    const float* cW1   = (const float*)d_in[2];
    const float* cb1   = (const float*)d_in[3];
    const float* cW2   = (const float*)d_in[4];
    const float* cb2   = (const float*)d_in[5];
    const float* pW1   = (const float*)d_in[6];
    const float* pb1   = (const float*)d_in[7];
    const float* pW2   = (const float*)d_in[8];
    const float* pb2   = (const float*)d_in[9];
    float* out = (float*)d_out;
    float* ws  = (float*)d_ws;

    float* phases_T = ws;                         // 65536 f32
    float* c0_T     = ws + 65536;                 // 65536
    float* tdiff_T  = ws + 131072;                // 65536
    float* H1_T     = ws + 196608;                // 32768
    float* H2_T     = ws + 229376;                // 32768

    phase_kernel<<<BB * TT, 256, 0, stream>>>(x, taper, phases_T, c0_T);
    tdiff_kernel<<<BB * TT / 256, 256, 0, stream>>>(c0_T, tdiff_T);
    gemm_kernel<TT, 0><<<512, 256, 0, stream>>>(phases_T, cW1, cb1, H1_T,
                                                tdiff_T, pW1, pb1, H2_T);
    gemm_kernel<HALF, 1><<<512, 256, 0, stream>>>(H1_T, cW2, cb2, out,
                                                  H2_T, pW2, pb2, out);
}

// Round 5
// 172.062 us; speedup vs baseline: 3.0577x; 1.0602x over previous
//
#include <hip/hip_runtime.h>
#include <math.h>

#define BB 16
#define TT 4096
#define EE 1024
#define HALF 2048
#define WIN 15
#define EPSF 1e-6f
#define PI_F   3.14159265358979323846f
#define PIO2_F 1.57079632679489662f

// Branchless cephes-style asin: ~16 VALU ops, 1 sqrt, no divergence.
__device__ __forceinline__ float fast_asinf(float v) {
    float a  = fabsf(v);
    float z1 = a * a;
    float z2 = 0.5f * (1.0f - a);
    bool big = a > 0.5f;
    float z = big ? z2 : z1;
    float s = big ? sqrtf(z) : a;
    float p = fmaf(z, 4.2163199048e-2f, 2.4181311049e-2f);
    p = fmaf(z, p, 4.5470025998e-2f);
    p = fmaf(z, p, 7.4953002686e-2f);
    p = fmaf(z, p, 1.6666752422e-1f);
    float r = fmaf(s * z, p, s);
    float rb = fmaf(-2.0f, r, PIO2_F);
    r = big ? rb : r;
    return copysignf(r, v);
}

// ---------------------------------------------------------------------------
// Phase kernel (R2 structure, measured 164-172 us total): wave per row.
// ---------------------------------------------------------------------------
__global__ void phase_kernel(const float* __restrict__ x,
                             const float* __restrict__ taper,
                             float* __restrict__ phases_T,
                             float* __restrict__ c0_T) {
    const int wave = threadIdx.x >> 6;
    const int lane = threadIdx.x & 63;
    const int row  = blockIdx.x * 4 + wave;      // [0, B*T)
    const int b = row >> 12;
    const int t = row & (TT - 1);
    const float tap = taper[t];
    const float* xr = x + (size_t)row * EE;

    const float c0 = xr[0] * tap;
    const float r = fabsf(c0) + EPSF;
    const float scale = tap / r;
    const float start = (c0 >= 0.0f) ? 0.0f : PI_F;
    const float LO = -1.0f + EPSF, HI = 1.0f - EPSF;

    const float4* xr4 = (const float4*)xr;
    float sum = 0.0f;
    #pragma unroll
    for (int j = 0; j < 4; ++j) {
        float4 v = xr4[j * 64 + lane];
        float a0 = fast_asinf(fminf(fmaxf(v.x * scale, LO), HI));
        if ((j | lane) == 0) a0 = 0.0f;          // element 0 excluded
        sum += a0;
        sum += fast_asinf(fminf(fmaxf(v.y * scale, LO), HI));
        sum += fast_asinf(fminf(fmaxf(v.z * scale, LO), HI));
        sum += fast_asinf(fminf(fmaxf(v.w * scale, LO), HI));
    }
    #pragma unroll
    for (int off = 32; off > 0; off >>= 1)
        sum += __shfl_xor(sum, off, 64);

    if (lane == 0) {
        phases_T[t * BB + b] = start + sum;
        c0_T[t * BB + b]     = c0;
    }
}

// ---------------------------------------------------------------------------
// tdiff: causal triangular moving average (window 15). Unchanged.
// ---------------------------------------------------------------------------
__global__ void tdiff_kernel(const float* __restrict__ c0_T,
                             float* __restrict__ tdiff_T) {
    const int f = blockIdx.x * blockDim.x + threadIdx.x;
    if (f >= BB * TT) return;
    const int t = f >> 4;
    const int b = f & 15;
    float num = 0.0f;
    #pragma unroll
    for (int d = 1; d <= WIN; ++d) {
        if (d <= t) num += (float)d * c0_T[(t - d) * BB + b];
    }
    const int s = (t < WIN) ? t : WIN;
    const float norm = 0.5f * (float)s * (float)(s + 1);
    tdiff_T[f] = (norm > 0.0f) ? (num / norm) : 0.0f;
}

// ---------------------------------------------------------------------------
// NEW GEMM: weight-streaming with global_load_lds double-buffer (2-phase).
// Block = 256 threads (4 waves), 8 output cols (2 per wave), full K.
// Per tile (BK=256 k): stage next W-tile async -> LDS, compute current from
// LDS(w) x global(A, L1/L2-hot). One __syncthreads per tile. Butterfly
// reduce in-wave, lane0/lane32 write the 16 outputs per col.
// MODE 0: silu -> H_T[o*16+b].   MODE 1: tanh -> out[b*4096 + o*2 + g].
// ---------------------------------------------------------------------------
__device__ __forceinline__ void gld_lds16(const float* g, float* l) {
    __builtin_amdgcn_global_load_lds(
        (const __attribute__((address_space(1))) unsigned int*)g,
        (__attribute__((address_space(3))) unsigned int*)l,
        16, 0, 0);
}

template <int K, int MODE>
__global__ void __launch_bounds__(256)
gemm_kernel(const float* __restrict__ A0, const float* __restrict__ W0,
            const float* __restrict__ bias0, float* __restrict__ out0,
            const float* __restrict__ A1, const float* __restrict__ W1,
            const float* __restrict__ bias1, float* __restrict__ out1) {
    const int BK = 256;
    const int NT = K / BK;
    __shared__ float wbuf[2][8 * BK];             // 2 x 8 KiB

    const int nb = HALF / 8;                      // 256 blocks per problem
    const int g = blockIdx.x / nb;
    const int obase = (blockIdx.x % nb) * 8;

    const float* A    = g ? A1 : A0;
    const float* W    = g ? W1 : W0;
    const float* bias = g ? bias1 : bias0;
    float* out        = g ? out1 : out0;

    const int wv   = threadIdx.x >> 6;            // 0..3
    const int lane = threadIdx.x & 63;
    const int c0 = wv * 2, c1 = wv * 2 + 1;       // cols in block
    const float4* A4 = (const float4*)A;

    // stage tile t into buffer s: each wave stages rows wv and wv+4 (1 KiB each)
    auto stage = [&](int t, int s) {
        #pragma unroll
        for (int i = 0; i < 2; ++i) {
            const int rr = wv + 4 * i;
            const float* src = W + (size_t)(obase + rr) * K + t * BK + lane * 4;
            float* dst = &wbuf[s][rr * BK];       // wave-uniform base; HW adds lane*16B
            gld_lds16(src, dst);
        }
    };

    float acc0[16], acc1[16];
    #pragma unroll
    for (int i = 0; i < 16; ++i) { acc0[i] = 0.0f; acc1[i] = 0.0f; }

    stage(0, 0);
    __syncthreads();                              // drains vmcnt -> buf0 ready

    int cur = 0;
    for (int t = 0; t < NT; ++t) {
        if (t + 1 < NT) stage(t + 1, cur ^ 1);    // async prefetch next tile

        const int kb = t * BK + lane * 4;         // this lane's 4 k values
        float4 a[4][4];
        #pragma unroll
        for (int j = 0; j < 4; ++j)
            #pragma unroll
            for (int q = 0; q < 4; ++q)
                a[j][q] = A4[(size_t)(kb + j) * 4 + q];

        float4 w0v = *(const float4*)&wbuf[cur][c0 * BK + lane * 4];
        float4 w1v = *(const float4*)&wbuf[cur][c1 * BK + lane * 4];
        float wA[4] = {w0v.x, w0v.y, w0v.z, w0v.w};
        float wB[4] = {w1v.x, w1v.y, w1v.z, w1v.w};

        #pragma unroll
        for (int j = 0; j < 4; ++j) {
            const float wa = wA[j], wb = wB[j];
            acc0[0]+=wa*a[j][0].x; acc0[1]+=wa*a[j][0].y; acc0[2]+=wa*a[j][0].z; acc0[3]+=wa*a[j][0].w;
            acc0[4]+=wa*a[j][1].x; acc0[5]+=wa*a[j][1].y; acc0[6]+=wa*a[j][1].z; acc0[7]+=wa*a[j][1].w;
            acc0[8]+=wa*a[j][2].x; acc0[9]+=wa*a[j][2].y; acc0[10]+=wa*a[j][2].z; acc0[11]+=wa*a[j][2].w;
            acc0[12]+=wa*a[j][3].x; acc0[13]+=wa*a[j][3].y; acc0[14]+=wa*a[j][3].z; acc0[15]+=wa*a[j][3].w;
            acc1[0]+=wb*a[j][0].x; acc1[1]+=wb*a[j][0].y; acc1[2]+=wb*a[j][0].z; acc1[3]+=wb*a[j][0].w;
            acc1[4]+=wb*a[j][1].x; acc1[5]+=wb*a[j][1].y; acc1[6]+=wb*a[j][1].z; acc1[7]+=wb*a[j][1].w;
            acc1[8]+=wb*a[j][2].x; acc1[9]+=wb*a[j][2].y; acc1[10]+=wb*a[j][2].z; acc1[11]+=wb*a[j][2].w;
            acc1[12]+=wb*a[j][3].x; acc1[13]+=wb*a[j][3].y; acc1[14]+=wb*a[j][3].z; acc1[15]+=wb*a[j][3].w;
        }
        __syncthreads();                          // drain stage loads, flip buffers
        cur ^= 1;
    }

    // full-wave butterfly: afterwards every lane holds the complete sums
    #pragma unroll
    for (int off = 32; off > 0; off >>= 1) {
        #pragma unroll
        for (int i = 0; i < 16; ++i) {
            acc0[i] += __shfl_xor(acc0[i], off, 64);
            acc1[i] += __shfl_xor(acc1[i], off, 64);
        }
    }

    const bool w0w = (lane == 0), w1w = (lane == 32);
    if (w0w || w1w) {
        const int c = w0w ? c0 : c1;
        const int o = obase + c;
        const float bs = bias[o];
        float v[16];
        #pragma unroll
        for (int i = 0; i < 16; ++i) {
            float s = (w0w ? acc0[i] : acc1[i]) + bs;
            if (MODE == 0) s = s / (1.0f + expf(-s));
            else           s = tanhf(s);
            v[i] = s;
        }
        if (MODE == 0) {
            float4* dst = (float4*)&out[o * BB];
            dst[0] = make_float4(v[0], v[1], v[2], v[3]);
            dst[1] = make_float4(v[4], v[5], v[6], v[7]);
            dst[2] = make_float4(v[8], v[9], v[10], v[11]);
            dst[3] = make_float4(v[12], v[13], v[14], v[15]);
        } else {
            #pragma unroll
            for (int i = 0; i < 16; ++i)
                out[(size_t)i * (HALF * 2) + o * 2 + g] = v[i];
        }
    }
}

extern "C" void kernel_launch(void* const* d_in, const int* in_sizes, int n_in,
                              void* d_out, int out_size, void* d_ws, size_t ws_size,
                              hipStream_t stream) {
    const float* x     = (const float*)d_in[0];
    const float* taper = (const float*)d_in[1];
    const float* cW1   = (const float*)d_in[2];
    const float* cb1   = (const float*)d_in[3];
    const float* cW2   = (const float*)d_in[4];
    const float* cb2   = (const float*)d_in[5];
    const float* pW1   = (const float*)d_in[6];
    const float* pb1   = (const float*)d_in[7];
    const float* pW2   = (const float*)d_in[8];
    const float* pb2   = (const float*)d_in[9];
    float* out = (float*)d_out;
    float* ws  = (float*)d_ws;

    float* phases_T = ws;                         // 65536 f32
    float* c0_T     = ws + 65536;
    float* tdiff_T  = ws + 131072;
    float* H1_T     = ws + 196608;
    float* H2_T     = ws + 229376;

    phase_kernel<<<BB * TT / 4, 256, 0, stream>>>(x, taper, phases_T, c0_T);
    tdiff_kernel<<<BB * TT / 256, 256, 0, stream>>>(c0_T, tdiff_T);
    gemm_kernel<TT, 0><<<512, 256, 0, stream>>>(phases_T, cW1, cb1, H1_T,
                                                tdiff_T, pW1, pb1, H2_T);
    gemm_kernel<HALF, 1><<<512, 256, 0, stream>>>(H1_T, cW2, cb2, out,
                                                  H2_T, pW2, pb2, out);
}